// Round 1
// 131.450 us; speedup vs baseline: 1.2162x; 1.2162x over previous
//
#include <hip/hip_runtime.h>
#include <hip/hip_bf16.h>

// Attention_82841329205539: B=2, N=2048, C=768, H=12, D=64, window=129
// Inputs fp32 (dict order), OUTPUT fp32 [B,N,C].
// r6:1485 r7:809 r8:444 r10:270 r11:275 r12:253 r13:166.6 r14:159.9 us.
// r14 analysis: qkv 46us @ MfmaUtil 11% / VALU 32% / occ 22% -> latency-bound
// reg-staging chain (fp32 load -> cvt -> LDS write). This round: bf16 pre-
// convert pass (cvt3), qkv+proj rebuilt on global_load_lds dwordx4 direct
// staging (m97 structure) + bijective XOR-swizzle (pre-swizzled source,
// swizzled ds_read) for conflict-free fragment reads. swin unchanged.
#define Bsz   2
#define Nseq  2048
#define Cdim  768
#define E3    2304
#define Hh    12
#define Dd    64
#define HALF  64
#define SCALEF 0.125f

typedef __attribute__((ext_vector_type(8))) short short8;
typedef __attribute__((ext_vector_type(4))) float f32x4;

__device__ __forceinline__ unsigned short f2bf(float f) {
    unsigned int u = __float_as_uint(f);
    u = (u + 0x7FFFu + ((u >> 16) & 1u)) >> 16;
    return (unsigned short)u;
}
__device__ __forceinline__ unsigned int pk2(float a, float b) {
    __hip_bfloat162 h = __float22bfloat162_rn(make_float2(a, b));
    union { __hip_bfloat162 h2; unsigned int u; } cv; cv.h2 = h; return cv.u;
}
__device__ __forceinline__ uint4 cvt8(const float4& lo, const float4& hi) {
    return make_uint4(pk2(lo.x, lo.y), pk2(lo.z, lo.w),
                      pk2(hi.x, hi.y), pk2(hi.z, hi.w));
}

// global -> LDS direct DMA, 16B per lane. LDS dest is wave-uniform base +
// lane*16 (linear); global src is per-lane (carries the swizzle).
__device__ __forceinline__ void gl_lds16(const unsigned short* g, unsigned short* l) {
    __builtin_amdgcn_global_load_lds(
        (__attribute__((address_space(1))) void*)(g),
        (__attribute__((address_space(3))) void*)(l), 16, 0, 0);
}

#define AST 72

// ---------------------------------------------------------------------------
// Kernel 0: fp32 -> bf16 pre-convert (x, w_qkv, w_proj). 22MB read, 11MB
// write; one 8-elem group per thread, grid 2688x256 exact.
// ---------------------------------------------------------------------------
__global__ __launch_bounds__(256) void cvt3(
    const float* __restrict__ x, const float* __restrict__ wq,
    const float* __restrict__ wp, unsigned short* __restrict__ xb,
    unsigned short* __restrict__ wqb, unsigned short* __restrict__ wpb)
{
    const int gid = blockIdx.x * 256 + threadIdx.x;   // 0..688127
    const float* src; unsigned short* dst; int off;
    if (gid < 393216)      { src = x;  dst = xb;  off = gid; }
    else if (gid < 614400) { src = wq; dst = wqb; off = gid - 393216; }
    else                   { src = wp; dst = wpb; off = gid - 614400; }
    const float4 lo = *(const float4*)&src[(size_t)off * 8];
    const float4 hi = *(const float4*)&src[(size_t)off * 8 + 4];
    *(uint4*)&dst[(size_t)off * 8] = cvt8(lo, hi);
}

// ---------------------------------------------------------------------------
// Kernel 1: QKV GEMM, pure bf16. 128Mx64N, BK=64, global_load_lds staging,
// XOR-swizzled LDS ([r][64] shorts, stored = logical ^ ((r&7)<<3)).
// LDS 24KB -> 6 blk/CU cap; grid (36,32) XCD-swizzled (whole grid resident).
// ---------------------------------------------------------------------------
__global__ __launch_bounds__(256) void qkv_mfma(
    const unsigned short* __restrict__ xb, const unsigned short* __restrict__ wqb,
    unsigned short* __restrict__ qkvb)
{
    __shared__ __align__(16) unsigned short smem[12288];   // 24 KB
    unsigned short* Asm = smem;          // [128][64] swizzled
    unsigned short* Bsm = smem + 8192;   // [64][64]  swizzled

    const int t  = threadIdx.x;
    const int id = blockIdx.y * 36 + blockIdx.x;
    const int p8 = id & 7, jb2 = id >> 3;
    const int bx = (p8 & 3) * 9 + (jb2 % 9);
    const int by = (p8 >> 2) * 16 + (jb2 / 9);
    const int row0 = by * 128, col0 = bx * 64;

    const int lane = t & 63, wave = t >> 6;
    const int wm = wave >> 1, wn = wave & 1;
    const int ln = lane & 15, quad = lane >> 4;
    const int lr  = lane >> 3;                     // row within 8-row chunk
    const int sc  = ((lane ^ lr) & 7) * 8;         // pre-swizzled src col (shorts)
    const int xsw = (ln & 7) << 3;                 // read-side XOR (shorts)

    f32x4 acc[4][2] = {};

    for (int k0 = 0; k0 < Cdim; k0 += 64) {
        __syncthreads();                 // prev-iter LDS reads complete
#pragma unroll
        for (int j = 0; j < 4; ++j)      // A: wave stages rows wave*32..+31
            gl_lds16(&xb[(size_t)(row0 + wave*32 + j*8 + lr) * Cdim + k0 + sc],
                     &Asm[(wave*4 + j) * 512]);
#pragma unroll
        for (int j = 0; j < 2; ++j)      // B: wave stages rows wave*16..+15
            gl_lds16(&wqb[(size_t)(col0 + wave*16 + j*8 + lr) * Cdim + k0 + sc],
                     &Bsm[(wave*2 + j) * 512]);
        __syncthreads();                 // vmcnt(0) drain -> tile ready
#pragma unroll
        for (int kk = 0; kk < 2; ++kk) {
            short8 af[4], bf[2];
#pragma unroll
            for (int mi = 0; mi < 4; ++mi)
                af[mi] = *(const short8*)&Asm[(wm*64 + mi*16 + ln)*64
                                              + ((kk*32 + quad*8) ^ xsw)];
#pragma unroll
            for (int ni = 0; ni < 2; ++ni)
                bf[ni] = *(const short8*)&Bsm[(wn*32 + ni*16 + ln)*64
                                              + ((kk*32 + quad*8) ^ xsw)];
#pragma unroll
            for (int mi = 0; mi < 4; ++mi)
#pragma unroll
                for (int ni = 0; ni < 2; ++ni)
                    acc[mi][ni] = __builtin_amdgcn_mfma_f32_16x16x32_bf16(
                        af[mi], bf[ni], acc[mi][ni], 0, 0, 0);
        }
    }

    __syncthreads();
    unsigned short (*Cs)[AST] = (unsigned short(*)[AST])smem;   // 18432 B
    const int rA = t >> 3, c8 = t & 7;
#pragma unroll
    for (int mi = 0; mi < 4; ++mi)
#pragma unroll
        for (int ni = 0; ni < 2; ++ni)
#pragma unroll
            for (int reg = 0; reg < 4; ++reg)
                Cs[wm*64 + mi*16 + quad*4 + reg][wn*32 + ni*16 + ln] =
                    f2bf(acc[mi][ni][reg]);
    __syncthreads();
#pragma unroll
    for (int j = 0; j < 4; ++j)
        *(uint4*)&qkvb[(size_t)(row0 + rA + j*32) * E3 + col0 + c8*8] =
            *(const uint4*)&Cs[rA + j*32][c8*8];
}

// ---------------------------------------------------------------------------
// Kernel 3: output projection + bias -> fp32. 64x64 tile, BK=64, both
// operands bf16 via global_load_lds + swizzle. LDS 16KB. grid (12,64).
// ---------------------------------------------------------------------------
__global__ __launch_bounds__(256) void proj_mfma(
    const unsigned short* __restrict__ Ab, const unsigned short* __restrict__ wpb,
    const float* __restrict__ bias, float* __restrict__ out)
{
    __shared__ __align__(16) unsigned short smem[8192];   // 16 KB
    unsigned short* Asm = smem;          // [64][64] swizzled
    unsigned short* Bsm = smem + 4096;   // [64][64] swizzled

    const int t  = threadIdx.x;
    const int id = blockIdx.y * 12 + blockIdx.x;
    const int p8 = id & 7, j2 = id >> 3;
    const int bx = j2 % 12;
    const int by = p8 * 8 + j2 / 12;
    const int row0 = by * 64, col0 = bx * 64;

    const int lane = t & 63, wave = t >> 6;
    const int ln = lane & 15, quad = lane >> 4;
    const int lr  = lane >> 3;
    const int sc  = ((lane ^ lr) & 7) * 8;
    const int xsw = (ln & 7) << 3;

    f32x4 acc[4] = {};

    for (int k0 = 0; k0 < Cdim; k0 += 64) {
        __syncthreads();
#pragma unroll
        for (int j = 0; j < 2; ++j) {
            const int r = wave*16 + j*8 + lr;
            gl_lds16(&Ab[(size_t)(row0 + r) * Cdim + k0 + sc],
                     &Asm[(wave*2 + j) * 512]);
            gl_lds16(&wpb[(size_t)(col0 + r) * Cdim + k0 + sc],
                     &Bsm[(wave*2 + j) * 512]);
        }
        __syncthreads();
#pragma unroll
        for (int kc = 0; kc < 2; ++kc) {
            short8 af = *(const short8*)&Asm[(wave*16 + ln)*64
                                             + ((kc*32 + quad*8) ^ xsw)];
#pragma unroll
            for (int ni = 0; ni < 4; ++ni) {
                short8 bf = *(const short8*)&Bsm[(ni*16 + ln)*64
                                                 + ((kc*32 + quad*8) ^ xsw)];
                acc[ni] = __builtin_amdgcn_mfma_f32_16x16x32_bf16(af, bf, acc[ni], 0, 0, 0);
            }
        }
    }

    // epilogue: two 32-col fp32 passes via LDS, fused bias
    float (*Csf)[36] = (float(*)[36])smem;   // 64 x 36 fp32 = 9216 B
#pragma unroll
    for (int p = 0; p < 2; ++p) {
        __syncthreads();
#pragma unroll
        for (int ni = 0; ni < 2; ++ni) {
            const int nn = p * 2 + ni;
#pragma unroll
            for (int reg = 0; reg < 4; ++reg)
                Csf[wave*16 + quad*4 + reg][ni*16 + ln] = acc[nn][reg];
        }
        __syncthreads();
#pragma unroll
        for (int j = 0; j < 2; ++j) {
            const int F = t + j * 256, r = F >> 3, c4 = F & 7;
            const int col = col0 + p * 32 + c4 * 4;
            float4 v  = *(const float4*)&Csf[r][c4 * 4];
            float4 bv = *(const float4*)&bias[col];
            *(float4*)&out[(size_t)(row0 + r) * Cdim + col] =
                make_float4(v.x + bv.x, v.y + bv.y, v.z + bv.z, v.w + bv.w);
        }
    }
}

// ---------------------------------------------------------------------------
// Kernel 2: MFMA sliding-window attention, Vt overlaid on Ks (LDS 34.8KB ->
// 4 blk/CU). V prefetched to registers; Q frags from global. 3 barriers.
// grid (64, 24), 256 thr. (unchanged this round)
// ---------------------------------------------------------------------------
#define TQ   32
#define ROWS 160
#define KST  72
#define VST  168

__global__ __launch_bounds__(256) void swin_attn(
    const unsigned short* __restrict__ qkvb, unsigned short* __restrict__ ab)
{
    __shared__ __align__(16) unsigned short SH[ROWS * KST];  // 23040 B (Ks/Vt)
    __shared__ __align__(16) unsigned short Pl[TQ][VST];     // 10752 B
    __shared__ float pmax[4][TQ];                            //   512 B
    __shared__ float psum[4][TQ];                            //   512 B
    unsigned short (*Ks)[KST] = (unsigned short(*)[KST])SH;
    unsigned short (*Vt)[VST] = (unsigned short(*)[VST])SH;  // overlay

    const int t  = threadIdx.x;
    const int bh = blockIdx.y;
    const int b  = bh / Hh, h = bh % Hh;
    const int i0 = blockIdx.x * TQ;
    const int hoff = h * Dd;

    const int lane = t & 63, wave = t >> 6;
    const int ln = lane & 15, quad = lane >> 4;
    const int mi    = wave & 1;     // query half (S phase)
    const int khalf = wave >> 1;    // key half (S phase)

    // ---- prefetch: Q frags (regs), V rows (regs); stage K -> LDS
    short8 qf[2];
#pragma unroll
    for (int kc = 0; kc < 2; ++kc)
        qf[kc] = *(const short8*)&qkvb[(size_t)(b * Nseq + i0 + mi*16 + ln) * E3
                                       + hoff + kc*32 + quad*8];
    uint4 vreg[5];
    const int rV = t >> 3, c8 = t & 7;
#pragma unroll
    for (int j = 0; j < 5; ++j) {
        const int r = rV + j * 32;            // key row 0..159
        const int g = i0 - HALF + r;
        uint4 v = make_uint4(0u, 0u, 0u, 0u);
        if (g >= 0 && g < Nseq)
            v = *(const uint4*)&qkvb[(size_t)(b * Nseq + g) * E3 + 2*Cdim + hoff + c8*8];
        vreg[j] = v;
    }
#pragma unroll
    for (int j = 0; j < 5; ++j) {
        const int r = rV + j * 32;
        const int g = i0 - HALF + r;
        uint4 v = make_uint4(0u, 0u, 0u, 0u);
        if (g >= 0 && g < Nseq)
            v = *(const uint4*)&qkvb[(size_t)(b * Nseq + g) * E3 + Cdim + hoff + c8*8];
        *(uint4*)&Ks[r][c8 * 8] = v;
    }
    __syncthreads();

    // ---- S phase
    f32x4 sacc[5] = {};
#pragma unroll
    for (int kc = 0; kc < 2; ++kc)
#pragma unroll
        for (int tt = 0; tt < 5; ++tt) {
            short8 kf = *(const short8*)&Ks[(khalf*5 + tt)*16 + ln][kc*32 + quad*8];
            sacc[tt] = __builtin_amdgcn_mfma_f32_16x16x32_bf16(qf[kc], kf, sacc[tt], 0, 0, 0);
        }

    float p[5][4];
    float pm[4] = {-1e30f, -1e30f, -1e30f, -1e30f};
#pragma unroll
    for (int tt = 0; tt < 5; ++tt) {
        const int j = (khalf*5 + tt)*16 + ln;
        const int g = i0 - HALF + j;
#pragma unroll
        for (int reg = 0; reg < 4; ++reg) {
            const int q = mi*16 + quad*4 + reg;
            const bool valid = (j >= q) && (j <= q + 2*HALF) && (g >= 0) && (g < Nseq);
            const float s = valid ? sacc[tt][reg] * SCALEF : -1e30f;
            p[tt][reg] = s;
            pm[reg] = fmaxf(pm[reg], s);
        }
    }
#pragma unroll
    for (int reg = 0; reg < 4; ++reg) {
        pm[reg] = fmaxf(pm[reg], __shfl_xor(pm[reg], 1));
        pm[reg] = fmaxf(pm[reg], __shfl_xor(pm[reg], 2));
        pm[reg] = fmaxf(pm[reg], __shfl_xor(pm[reg], 4));
        pm[reg] = fmaxf(pm[reg], __shfl_xor(pm[reg], 8));
    }
    if (ln == 0)
#pragma unroll
        for (int reg = 0; reg < 4; ++reg)
            pmax[wave][mi*16 + quad*4 + reg] = pm[reg];
    __syncthreads();   // pmax ready; all Ks reads complete (Vt overlay safe)

    // ---- exp, row sums, write P; overwrite Ks region with Vt
    float ps[4] = {};
#pragma unroll
    for (int reg = 0; reg < 4; ++reg) {
        const int q = mi*16 + quad*4 + reg;
        const float cm = fmaxf(pmax[mi][q], pmax[mi | 2][q]);
#pragma unroll
        for (int tt = 0; tt < 5; ++tt) {
            const float pv = (p[tt][reg] > -1e29f) ? __expf(p[tt][reg] - cm) : 0.f;
            p[tt][reg] = pv;
            ps[reg] += pv;
        }
    }
#pragma unroll
    for (int reg = 0; reg < 4; ++reg) {
        ps[reg] += __shfl_xor(ps[reg], 1);
        ps[reg] += __shfl_xor(ps[reg], 2);
        ps[reg] += __shfl_xor(ps[reg], 4);
        ps[reg] += __shfl_xor(ps[reg], 8);
    }
    if (ln == 0)
#pragma unroll
        for (int reg = 0; reg < 4; ++reg)
            psum[wave][mi*16 + quad*4 + reg] = ps[reg];
#pragma unroll
    for (int tt = 0; tt < 5; ++tt)
#pragma unroll
        for (int reg = 0; reg < 4; ++reg)
            Pl[mi*16 + quad*4 + reg][(khalf*5 + tt)*16 + ln] = f2bf(p[tt][reg]);
    // Vt[dim][key] from vreg (transpose scalar stores)
#pragma unroll
    for (int j = 0; j < 5; ++j) {
        const int r = rV + j * 32;
        union { unsigned short us[8]; uint4 u; } pk; pk.u = vreg[j];
#pragma unroll
        for (int jj = 0; jj < 8; ++jj)
            Vt[c8 * 8 + jj][r] = pk.us[jj];
    }
    __syncthreads();

    // ---- PV phase: D[m=dim][n=query] = Vt . Pl^T
    const int niq = wave & 1;
    const int mb  = (wave >> 1) * 2;
    f32x4 oacc[2] = {};
#pragma unroll
    for (int kc = 0; kc < 5; ++kc) {
        short8 pf = *(const short8*)&Pl[niq*16 + ln][kc*32 + quad*8];
#pragma unroll
        for (int m2 = 0; m2 < 2; ++m2) {
            short8 vf = *(const short8*)&Vt[(mb + m2)*16 + ln][kc*32 + quad*8];
            oacc[m2] = __builtin_amdgcn_mfma_f32_16x16x32_bf16(vf, pf, oacc[m2], 0, 0, 0);
        }
    }

    const int q = niq*16 + ln;
    const float inv = 1.f / (psum[q >> 4][q] + psum[(q >> 4) | 2][q]);
    unsigned short* orow = &ab[(size_t)(b * Nseq + i0 + q) * Cdim + hoff];
#pragma unroll
    for (int m2 = 0; m2 < 2; ++m2) {
        const int d0 = (mb + m2)*16 + quad*4;
        union { unsigned short us[4]; uint2 u2; } pk;
#pragma unroll
        for (int reg = 0; reg < 4; ++reg)
            pk.us[reg] = f2bf(oacc[m2][reg] * inv);
        *(uint2*)&orow[d0] = pk.u2;
    }
}

// ---------------------------------------------------------------------------
extern "C" void kernel_launch(void* const* d_in, const int* in_sizes, int n_in,
                              void* d_out, int out_size, void* d_ws, size_t ws_size,
                              hipStream_t stream)
{
    const float* x      = (const float*)d_in[0];
    const float* w_qkv  = (const float*)d_in[1];
    const float* w_proj = (const float*)d_in[2];
    const float* b_proj = (const float*)d_in[3];
    float* out = (float*)d_out;

    unsigned short* qkvb = (unsigned short*)d_ws;   // 9,437,184 shorts
    unsigned short* ab   = qkvb + 9437184;          // 3,145,728 shorts
    unsigned short* xb   = ab   + 3145728;          // 3,145,728 shorts
    unsigned short* wqb  = xb   + 3145728;          // 1,769,472 shorts
    unsigned short* wpb  = wqb  + 1769472;          //   589,824 shorts (36.2MB total)

    cvt3<<<dim3(2688), 256, 0, stream>>>(x, w_qkv, w_proj, xb, wqb, wpb);
    qkv_mfma<<<dim3(36, 32), 256, 0, stream>>>(xb, wqb, qkvb);
    swin_attn<<<dim3(Nseq / TQ, Bsz * Hh), 256, 0, stream>>>(qkvb, ab);
    proj_mfma<<<dim3(12, 64), 256, 0, stream>>>(ab, wpb, b_proj, out);
}